// Round 1
// baseline (247.205 us; speedup 1.0000x reference)
//
#include <hip/hip_runtime.h>
#include <math.h>

#define BATCH 8192
#define SEQ 50
#define EMB 512

// ---------------------------------------------------------------------------
// Kernel 1: embedding bag — one block per batch row, 256 threads, float2/lane.
// X[row][c] = mean_i E[ids[row][i]][c]
// ---------------------------------------------------------------------------
__global__ __launch_bounds__(256) void embed_bag(const int* __restrict__ ids,
                                                 const float* __restrict__ E,
                                                 float* __restrict__ X) {
  __shared__ int sid[SEQ];
  const int row = blockIdx.x;
  const int tid = threadIdx.x;
  if (tid < SEQ) sid[tid] = ids[row * SEQ + tid];
  __syncthreads();
  const int c = tid * 2;
  float ax = 0.f, ay = 0.f;
#pragma unroll 5
  for (int i = 0; i < SEQ; ++i) {
    const float2 v = *reinterpret_cast<const float2*>(&E[(size_t)sid[i] * EMB + c]);
    ax += v.x;
    ay += v.y;
  }
  float2 o;
  o.x = ax * (1.0f / SEQ);
  o.y = ay * (1.0f / SEQ);
  *reinterpret_cast<float2*>(&X[(size_t)row * EMB + c]) = o;
}

// ---------------------------------------------------------------------------
// Kernel 2: fp32 tiled GEMM + bias + ReLU.
// C[M][N] = relu(A[M][K] @ B[K][N] + bias), M=8192, N multiple of 64.
// 64x64 C-tile per block, BK=16, 256 threads, 4x4 micro-tile per thread.
// ---------------------------------------------------------------------------
template <int K, int N, bool RELU>
__global__ __launch_bounds__(256) void gemm_bias_act(const float* __restrict__ A,
                                                     const float* __restrict__ Bm,
                                                     const float* __restrict__ bias,
                                                     float* __restrict__ C) {
  __shared__ float As[16][64];  // transposed A tile: As[k][m]
  __shared__ float Bs[16][64];  // B tile: Bs[k][n]

  const int tid = threadIdx.x;
  const int tx = tid & 15;   // 0..15 -> 4 output cols each
  const int ty = tid >> 4;   // 0..15 -> 4 output rows each
  const int rowBase = blockIdx.y * 64;
  const int colBase = blockIdx.x * 64;

  float acc[4][4] = {};

  for (int kt = 0; kt < K; kt += 16) {
    // Stage A tile (64 rows x 16 k) transposed into LDS.
    {
      const int m = tid >> 2;             // 0..63
      const int kq = (tid & 3) * 4;       // 0,4,8,12
      const float4 a =
          *reinterpret_cast<const float4*>(&A[(size_t)(rowBase + m) * K + kt + kq]);
      As[kq + 0][m] = a.x;
      As[kq + 1][m] = a.y;
      As[kq + 2][m] = a.z;
      As[kq + 3][m] = a.w;
      // Stage B tile (16 k x 64 n), same layout as global.
      const int kr = tid >> 4;            // 0..15
      const int nq = (tid & 15) * 4;      // 0..60
      *reinterpret_cast<float4*>(&Bs[kr][nq]) =
          *reinterpret_cast<const float4*>(&Bm[(size_t)(kt + kr) * N + colBase + nq]);
    }
    __syncthreads();
#pragma unroll
    for (int k = 0; k < 16; ++k) {
      const float4 a = *reinterpret_cast<const float4*>(&As[k][ty * 4]);
      const float4 b = *reinterpret_cast<const float4*>(&Bs[k][tx * 4]);
      const float av[4] = {a.x, a.y, a.z, a.w};
      const float bv[4] = {b.x, b.y, b.z, b.w};
#pragma unroll
      for (int i = 0; i < 4; ++i)
#pragma unroll
        for (int j = 0; j < 4; ++j) acc[i][j] = fmaf(av[i], bv[j], acc[i][j]);
    }
    __syncthreads();
  }

  // Epilogue: bias + ReLU + coalesced float4 store.
  const float4 bb = *reinterpret_cast<const float4*>(&bias[colBase + tx * 4]);
  const float bv[4] = {bb.x, bb.y, bb.z, bb.w};
#pragma unroll
  for (int i = 0; i < 4; ++i) {
    const int r = rowBase + ty * 4 + i;
    float4 o;
    float* op = &o.x;
#pragma unroll
    for (int j = 0; j < 4; ++j) {
      float v = acc[i][j] + bv[j];
      if (RELU) v = fmaxf(v, 0.f);
      op[j] = v;
    }
    *reinterpret_cast<float4*>(&C[(size_t)r * N + colBase + tx * 4]) = o;
  }
}

// ---------------------------------------------------------------------------
// Kernel 3: final layer (K=64, N=3) + softmax. One thread per batch row.
// ---------------------------------------------------------------------------
__global__ __launch_bounds__(256) void final_softmax(const float* __restrict__ X,
                                                     const float* __restrict__ W,   // [64][3]
                                                     const float* __restrict__ bias,// [3]
                                                     float* __restrict__ Out) {    // [B][3]
  __shared__ float sw[64 * 3];
  __shared__ float sb[3];
  const int tid = threadIdx.x;
  if (tid < 64 * 3) sw[tid] = W[tid];
  if (tid < 3) sb[tid] = bias[tid];
  __syncthreads();

  const int row = blockIdx.x * 256 + tid;
  float d0 = sb[0], d1 = sb[1], d2 = sb[2];
#pragma unroll
  for (int k = 0; k < 64; k += 4) {
    const float4 x = *reinterpret_cast<const float4*>(&X[(size_t)row * 64 + k]);
    const float xv[4] = {x.x, x.y, x.z, x.w};
#pragma unroll
    for (int u = 0; u < 4; ++u) {
      d0 = fmaf(xv[u], sw[(k + u) * 3 + 0], d0);
      d1 = fmaf(xv[u], sw[(k + u) * 3 + 1], d1);
      d2 = fmaf(xv[u], sw[(k + u) * 3 + 2], d2);
    }
  }
  const float m = fmaxf(d0, fmaxf(d1, d2));
  const float e0 = expf(d0 - m);
  const float e1 = expf(d1 - m);
  const float e2 = expf(d2 - m);
  const float inv = 1.0f / (e0 + e1 + e2);
  Out[(size_t)row * 3 + 0] = e0 * inv;
  Out[(size_t)row * 3 + 1] = e1 * inv;
  Out[(size_t)row * 3 + 2] = e2 * inv;
}

// ---------------------------------------------------------------------------
extern "C" void kernel_launch(void* const* d_in, const int* in_sizes, int n_in,
                              void* d_out, int out_size, void* d_ws, size_t ws_size,
                              hipStream_t stream) {
  const int* ids = (const int*)d_in[0];
  const float* E = (const float*)d_in[1];
  const float* W0 = (const float*)d_in[2];
  const float* b0 = (const float*)d_in[3];
  const float* W1 = (const float*)d_in[4];
  const float* b1 = (const float*)d_in[5];
  const float* W2 = (const float*)d_in[6];
  const float* b2 = (const float*)d_in[7];
  const float* W3 = (const float*)d_in[8];
  const float* b3 = (const float*)d_in[9];
  const float* W4 = (const float*)d_in[10];
  const float* b4 = (const float*)d_in[11];
  float* out = (float*)d_out;

  // Ping-pong activation buffers in workspace (needs 2 * 8192*512*4 = 32 MB).
  float* xA = (float*)d_ws;
  float* xB = xA + (size_t)BATCH * EMB;

  embed_bag<<<BATCH, 256, 0, stream>>>(ids, E, xA);                              // xA [8192,512]
  gemm_bias_act<512, 512, true><<<dim3(8, 128), 256, 0, stream>>>(xA, W0, b0, xB); // xB [8192,512]
  gemm_bias_act<512, 256, true><<<dim3(4, 128), 256, 0, stream>>>(xB, W1, b1, xA); // xA [8192,256]
  gemm_bias_act<256, 128, true><<<dim3(2, 128), 256, 0, stream>>>(xA, W2, b2, xB); // xB [8192,128]
  gemm_bias_act<128, 64, true><<<dim3(1, 128), 256, 0, stream>>>(xB, W3, b3, xA);  // xA [8192,64]
  final_softmax<<<BATCH / 256, 256, 0, stream>>>(xA, W4, b4, out);               // out [8192,3]
}

// Round 2
// 164.084 us; speedup vs baseline: 1.5066x; 1.5066x over previous
//
#include <hip/hip_runtime.h>
#include <hip/hip_bf16.h>
#include <math.h>

#define BATCH 8192
#define SEQ 50
#define EMB 512

typedef __attribute__((ext_vector_type(8))) short bf16x8;
typedef __attribute__((ext_vector_type(4))) float f32x4;

static __device__ __forceinline__ ushort f2b(float v) {
  __hip_bfloat16 h = __float2bfloat16(v);
  return *reinterpret_cast<ushort*>(&h);
}
static __device__ __forceinline__ float b2f(ushort u) {
  unsigned int x = ((unsigned int)u) << 16;
  float f;
  __builtin_memcpy(&f, &x, 4);
  return f;
}

// ---------------------------------------------------------------------------
// Kernel 0: weight convert + transpose. Wt[n][k] = bf16(W[k][n]).
// blockIdx.y selects which matrix. Writes coalesced; re-reads absorbed by L2.
// ---------------------------------------------------------------------------
__global__ __launch_bounds__(256) void convert_weights(
    const float* __restrict__ W0, const float* __restrict__ W1,
    const float* __restrict__ W2, const float* __restrict__ W3,
    ushort* __restrict__ T0, ushort* __restrict__ T1,
    ushort* __restrict__ T2, ushort* __restrict__ T3) {
  const int idx = blockIdx.x * 256 + threadIdx.x;
  const int which = blockIdx.y;
  const float* W;
  ushort* T;
  int K, N;
  if (which == 0)      { W = W0; T = T0; K = 512; N = 512; }
  else if (which == 1) { W = W1; T = T1; K = 512; N = 256; }
  else if (which == 2) { W = W2; T = T2; K = 256; N = 128; }
  else                 { W = W3; T = T3; K = 128; N = 64; }
  if (idx >= K * N) return;
  const int n = idx / K;
  const int k = idx - n * K;
  T[idx] = f2b(W[k * N + n]);
}

// ---------------------------------------------------------------------------
// Kernel 1: embedding bag — fp32 gather/mean, bf16 store.
// ---------------------------------------------------------------------------
__global__ __launch_bounds__(256) void embed_bag(const int* __restrict__ ids,
                                                 const float* __restrict__ E,
                                                 ushort* __restrict__ X) {
  __shared__ int sid[SEQ];
  const int row = blockIdx.x;
  const int tid = threadIdx.x;
  if (tid < SEQ) sid[tid] = ids[row * SEQ + tid];
  __syncthreads();
  const int c = tid * 2;
  float ax = 0.f, ay = 0.f;
#pragma unroll 5
  for (int i = 0; i < SEQ; ++i) {
    const float2 v = *reinterpret_cast<const float2*>(&E[(size_t)sid[i] * EMB + c]);
    ax += v.x;
    ay += v.y;
  }
  ushort2 o;
  o.x = f2b(ax * (1.0f / SEQ));
  o.y = f2b(ay * (1.0f / SEQ));
  *reinterpret_cast<ushort2*>(&X[(size_t)row * EMB + c]) = o;
}

// ---------------------------------------------------------------------------
// Kernel 2: bf16 MFMA GEMM + bias + ReLU, bf16 out.
// C[M][N] = relu(A[M][K] @ Bt[N][K]^T + bias). Block tile 128x64, BK=64,
// 256 threads = 4 waves; each wave 32x64 via 2x4 frags of 16x16x32 MFMA.
// LDS rows padded to 72 elems (144 B) -> ~2-way bank aliasing (free, m136).
// ---------------------------------------------------------------------------
template <int K, int N, bool RELU>
__global__ __launch_bounds__(256) void gemm_mfma(const ushort* __restrict__ A,   // [M][K] bf16
                                                 const ushort* __restrict__ Bt,  // [N][K] bf16
                                                 const float* __restrict__ bias, // [N]
                                                 ushort* __restrict__ C) {       // [M][N] bf16
  __shared__ ushort As[128][72];
  __shared__ ushort Bs[64][72];
  const int tid = threadIdx.x;
  const int w = tid >> 6;
  const int l = tid & 63;
  const int r16 = l & 15;
  const int khi = l >> 4;
  const int rowBase = blockIdx.y * 128;
  const int colBase = blockIdx.x * 64;

  f32x4 acc[2][4] = {};

  for (int kt = 0; kt < K; kt += 64) {
    // Stage A tile: 128 rows x 64 k = 1024 x 16B chunks, 4 per thread.
#pragma unroll
    for (int i = 0; i < 4; ++i) {
      const int idx = i * 256 + tid;
      const int r = idx >> 3;
      const int kq = (idx & 7) * 8;
      *reinterpret_cast<int4*>(&As[r][kq]) =
          *reinterpret_cast<const int4*>(&A[(size_t)(rowBase + r) * K + kt + kq]);
    }
    // Stage B tile: 64 cols x 64 k = 512 x 16B chunks, 2 per thread.
#pragma unroll
    for (int i = 0; i < 2; ++i) {
      const int idx = i * 256 + tid;
      const int n = idx >> 3;
      const int kq = (idx & 7) * 8;
      *reinterpret_cast<int4*>(&Bs[n][kq]) =
          *reinterpret_cast<const int4*>(&Bt[(size_t)(colBase + n) * K + kt + kq]);
    }
    __syncthreads();
#pragma unroll
    for (int q = 0; q < 2; ++q) {
      const int ko = q * 32 + khi * 8;
      const bf16x8 a0 = *reinterpret_cast<const bf16x8*>(&As[w * 32 + r16][ko]);
      const bf16x8 a1 = *reinterpret_cast<const bf16x8*>(&As[w * 32 + 16 + r16][ko]);
      const bf16x8 b0 = *reinterpret_cast<const bf16x8*>(&Bs[r16][ko]);
      const bf16x8 b1 = *reinterpret_cast<const bf16x8*>(&Bs[16 + r16][ko]);
      const bf16x8 b2 = *reinterpret_cast<const bf16x8*>(&Bs[32 + r16][ko]);
      const bf16x8 b3 = *reinterpret_cast<const bf16x8*>(&Bs[48 + r16][ko]);
      acc[0][0] = __builtin_amdgcn_mfma_f32_16x16x32_bf16(a0, b0, acc[0][0], 0, 0, 0);
      acc[0][1] = __builtin_amdgcn_mfma_f32_16x16x32_bf16(a0, b1, acc[0][1], 0, 0, 0);
      acc[0][2] = __builtin_amdgcn_mfma_f32_16x16x32_bf16(a0, b2, acc[0][2], 0, 0, 0);
      acc[0][3] = __builtin_amdgcn_mfma_f32_16x16x32_bf16(a0, b3, acc[0][3], 0, 0, 0);
      acc[1][0] = __builtin_amdgcn_mfma_f32_16x16x32_bf16(a1, b0, acc[1][0], 0, 0, 0);
      acc[1][1] = __builtin_amdgcn_mfma_f32_16x16x32_bf16(a1, b1, acc[1][1], 0, 0, 0);
      acc[1][2] = __builtin_amdgcn_mfma_f32_16x16x32_bf16(a1, b2, acc[1][2], 0, 0, 0);
      acc[1][3] = __builtin_amdgcn_mfma_f32_16x16x32_bf16(a1, b3, acc[1][3], 0, 0, 0);
    }
    __syncthreads();
  }

  // Epilogue: C/D layout col = l&15, row = (l>>4)*4 + e.
#pragma unroll
  for (int n = 0; n < 4; ++n) {
    const float bv = bias[colBase + n * 16 + r16];
#pragma unroll
    for (int m = 0; m < 2; ++m) {
#pragma unroll
      for (int e = 0; e < 4; ++e) {
        const int rr = rowBase + w * 32 + m * 16 + khi * 4 + e;
        float v = acc[m][n][e] + bv;
        if (RELU) v = fmaxf(v, 0.f);
        C[(size_t)rr * N + colBase + n * 16 + r16] = f2b(v);
      }
    }
  }
}

// ---------------------------------------------------------------------------
// Kernel 3: final layer (K=64, N=3) + softmax. bf16 input, fp32 out.
// ---------------------------------------------------------------------------
__global__ __launch_bounds__(256) void final_softmax(const ushort* __restrict__ X,
                                                     const float* __restrict__ W,    // [64][3]
                                                     const float* __restrict__ bias, // [3]
                                                     float* __restrict__ Out) {      // [B][3]
  __shared__ float sw[64 * 3];
  __shared__ float sb[3];
  const int tid = threadIdx.x;
  if (tid < 64 * 3) sw[tid] = W[tid];
  if (tid < 3) sb[tid] = bias[tid];
  __syncthreads();

  const int row = blockIdx.x * 256 + tid;
  float d0 = sb[0], d1 = sb[1], d2 = sb[2];
#pragma unroll
  for (int k = 0; k < 64; k += 8) {
    const int4 xr = *reinterpret_cast<const int4*>(&X[(size_t)row * 64 + k]);
    const ushort* xp = reinterpret_cast<const ushort*>(&xr);
#pragma unroll
    for (int u = 0; u < 8; ++u) {
      const float x = b2f(xp[u]);
      d0 = fmaf(x, sw[(k + u) * 3 + 0], d0);
      d1 = fmaf(x, sw[(k + u) * 3 + 1], d1);
      d2 = fmaf(x, sw[(k + u) * 3 + 2], d2);
    }
  }
  const float m = fmaxf(d0, fmaxf(d1, d2));
  const float e0 = expf(d0 - m);
  const float e1 = expf(d1 - m);
  const float e2 = expf(d2 - m);
  const float inv = 1.0f / (e0 + e1 + e2);
  Out[(size_t)row * 3 + 0] = e0 * inv;
  Out[(size_t)row * 3 + 1] = e1 * inv;
  Out[(size_t)row * 3 + 2] = e2 * inv;
}

// ---------------------------------------------------------------------------
extern "C" void kernel_launch(void* const* d_in, const int* in_sizes, int n_in,
                              void* d_out, int out_size, void* d_ws, size_t ws_size,
                              hipStream_t stream) {
  const int* ids = (const int*)d_in[0];
  const float* E = (const float*)d_in[1];
  const float* W0 = (const float*)d_in[2];
  const float* b0 = (const float*)d_in[3];
  const float* W1 = (const float*)d_in[4];
  const float* b1 = (const float*)d_in[5];
  const float* W2 = (const float*)d_in[6];
  const float* b2 = (const float*)d_in[7];
  const float* W3 = (const float*)d_in[8];
  const float* b3 = (const float*)d_in[9];
  const float* W4 = (const float*)d_in[10];
  const float* b4 = (const float*)d_in[11];
  float* out = (float*)d_out;

  // Workspace layout: [Wt0 Wt1 Wt2 Wt3 | pad to 1MB | xA (8MB) | xB (8MB)]
  ushort* wt0 = (ushort*)d_ws;
  ushort* wt1 = wt0 + 512 * 512;
  ushort* wt2 = wt1 + 512 * 256;
  ushort* wt3 = wt2 + 256 * 128;
  ushort* xA = (ushort*)((char*)d_ws + (1u << 20));
  ushort* xB = xA + (size_t)BATCH * EMB;

  convert_weights<<<dim3(1024, 4), 256, 0, stream>>>(W0, W1, W2, W3, wt0, wt1, wt2, wt3);
  embed_bag<<<BATCH, 256, 0, stream>>>(ids, E, xA);                                    // xA [8192,512]
  gemm_mfma<512, 512, true><<<dim3(8, 64), 256, 0, stream>>>(xA, wt0, b0, xB);         // xB [8192,512]
  gemm_mfma<512, 256, true><<<dim3(4, 64), 256, 0, stream>>>(xB, wt1, b1, xA);         // xA [8192,256]
  gemm_mfma<256, 128, true><<<dim3(2, 64), 256, 0, stream>>>(xA, wt2, b2, xB);         // xB [8192,128]
  gemm_mfma<128, 64, true><<<dim3(1, 64), 256, 0, stream>>>(xB, wt3, b3, xA);          // xA [8192,64]
  final_softmax<<<BATCH / 256, 256, 0, stream>>>(xA, W4, b4, out);                     // out [8192,3]
}

// Round 4
// 162.664 us; speedup vs baseline: 1.5197x; 1.0087x over previous
//
#include <hip/hip_runtime.h>
#include <hip/hip_bf16.h>
#include <math.h>

#define BATCH 8192
#define SEQ 50
#define EMB 512
#define VOCAB 100000

typedef __attribute__((ext_vector_type(8))) short bf16x8;
typedef __attribute__((ext_vector_type(4))) float f32x4;
typedef __attribute__((ext_vector_type(4))) float fvec4;

static __device__ __forceinline__ ushort f2b(float v) {
  __hip_bfloat16 h = __float2bfloat16(v);
  return *reinterpret_cast<ushort*>(&h);
}
static __device__ __forceinline__ float b2f(ushort u) {
  unsigned int x = ((unsigned int)u) << 16;
  float f;
  __builtin_memcpy(&f, &x, 4);
  return f;
}
static __device__ __forceinline__ float lo_bf(unsigned int u) {
  unsigned int x = u << 16;
  float f;
  __builtin_memcpy(&f, &x, 4);
  return f;
}
static __device__ __forceinline__ float hi_bf(unsigned int u) {
  unsigned int x = u & 0xffff0000u;
  float f;
  __builtin_memcpy(&f, &x, 4);
  return f;
}

// ---------------------------------------------------------------------------
// Kernel -1: table convert fp32 -> bf16. Nontemporal reads keep the fp32
// stream out of L3 so the bf16 table stays resident across graph replays.
// ---------------------------------------------------------------------------
__global__ __launch_bounds__(256) void convert_table(const float* __restrict__ E,
                                                     ushort* __restrict__ Ebf) {
  const size_t total = (size_t)VOCAB * EMB;  // 51,200,000 (divisible by 8)
  size_t idx = ((size_t)blockIdx.x * 256 + threadIdx.x) * 8;
  const size_t stride = (size_t)gridDim.x * 256 * 8;
  for (; idx < total; idx += stride) {
    const fvec4 a = __builtin_nontemporal_load(reinterpret_cast<const fvec4*>(E + idx));
    const fvec4 b = __builtin_nontemporal_load(reinterpret_cast<const fvec4*>(E + idx + 4));
    ushort r[8];
    r[0] = f2b(a.x); r[1] = f2b(a.y); r[2] = f2b(a.z); r[3] = f2b(a.w);
    r[4] = f2b(b.x); r[5] = f2b(b.y); r[6] = f2b(b.z); r[7] = f2b(b.w);
    *reinterpret_cast<int4*>(&Ebf[idx]) = *reinterpret_cast<const int4*>(r);
  }
}

// ---------------------------------------------------------------------------
// Kernel 0: weight convert + transpose. Wt[n][k] = bf16(W[k][n]).
// ---------------------------------------------------------------------------
__global__ __launch_bounds__(256) void convert_weights(
    const float* __restrict__ W0, const float* __restrict__ W1,
    const float* __restrict__ W2, const float* __restrict__ W3,
    ushort* __restrict__ T0, ushort* __restrict__ T1,
    ushort* __restrict__ T2, ushort* __restrict__ T3) {
  const int idx = blockIdx.x * 256 + threadIdx.x;
  const int which = blockIdx.y;
  const float* W;
  ushort* T;
  int K, N;
  if (which == 0)      { W = W0; T = T0; K = 512; N = 512; }
  else if (which == 1) { W = W1; T = T1; K = 512; N = 256; }
  else if (which == 2) { W = W2; T = T2; K = 256; N = 128; }
  else                 { W = W3; T = T3; K = 128; N = 64; }
  if (idx >= K * N) return;
  const int n = idx / K;
  const int k = idx - n * K;
  T[idx] = f2b(W[k * N + n]);
}

// ---------------------------------------------------------------------------
// Kernel 1a: embedding bag over bf16 table. One WAVE per batch row; lane
// covers 8 bf16 columns (16 B load). 4 rows per 256-thread block.
// ---------------------------------------------------------------------------
__global__ __launch_bounds__(256) void embed_bag_bf16(const int* __restrict__ ids,
                                                      const ushort* __restrict__ Ebf,
                                                      ushort* __restrict__ X) {
  __shared__ int sid[4][SEQ];
  const int tid = threadIdx.x;
  if (tid < 4 * SEQ) sid[tid / SEQ][tid % SEQ] = ids[blockIdx.x * 4 * SEQ + tid];
  __syncthreads();
  const int w = tid >> 6;
  const int l = tid & 63;
  const int row = blockIdx.x * 4 + w;
  const int col = l * 8;
  float acc[8] = {};
#pragma unroll 5
  for (int i = 0; i < SEQ; ++i) {
    const uint4 v = *reinterpret_cast<const uint4*>(&Ebf[(size_t)sid[w][i] * EMB + col]);
    acc[0] += lo_bf(v.x); acc[1] += hi_bf(v.x);
    acc[2] += lo_bf(v.y); acc[3] += hi_bf(v.y);
    acc[4] += lo_bf(v.z); acc[5] += hi_bf(v.z);
    acc[6] += lo_bf(v.w); acc[7] += hi_bf(v.w);
  }
  ushort r[8];
#pragma unroll
  for (int k = 0; k < 8; ++k) r[k] = f2b(acc[k] * (1.0f / SEQ));
  *reinterpret_cast<int4*>(&X[(size_t)row * EMB + col]) = *reinterpret_cast<const int4*>(r);
}

// ---------------------------------------------------------------------------
// Kernel 1b (fallback, small ws): fp32-table bag, bf16 out. Block per row.
// ---------------------------------------------------------------------------
__global__ __launch_bounds__(256) void embed_bag_f32(const int* __restrict__ ids,
                                                     const float* __restrict__ E,
                                                     ushort* __restrict__ X) {
  __shared__ int sid[SEQ];
  const int row = blockIdx.x;
  const int tid = threadIdx.x;
  if (tid < SEQ) sid[tid] = ids[row * SEQ + tid];
  __syncthreads();
  const int c = tid * 2;
  float ax = 0.f, ay = 0.f;
#pragma unroll 5
  for (int i = 0; i < SEQ; ++i) {
    const float2 v = *reinterpret_cast<const float2*>(&E[(size_t)sid[i] * EMB + c]);
    ax += v.x;
    ay += v.y;
  }
  ushort2 o;
  o.x = f2b(ax * (1.0f / SEQ));
  o.y = f2b(ay * (1.0f / SEQ));
  *reinterpret_cast<ushort2*>(&X[(size_t)row * EMB + c]) = o;
}

// ---------------------------------------------------------------------------
// Kernel 2: bf16 MFMA GEMM + bias + ReLU, bf16 out. 128x64 tile, BK=64.
// ---------------------------------------------------------------------------
template <int K, int N, bool RELU>
__global__ __launch_bounds__(256) void gemm_mfma(const ushort* __restrict__ A,   // [M][K] bf16
                                                 const ushort* __restrict__ Bt,  // [N][K] bf16
                                                 const float* __restrict__ bias, // [N]
                                                 ushort* __restrict__ C) {       // [M][N] bf16
  __shared__ ushort As[128][72];
  __shared__ ushort Bs[64][72];
  const int tid = threadIdx.x;
  const int w = tid >> 6;
  const int l = tid & 63;
  const int r16 = l & 15;
  const int khi = l >> 4;
  const int rowBase = blockIdx.y * 128;
  const int colBase = blockIdx.x * 64;

  f32x4 acc[2][4] = {};

  for (int kt = 0; kt < K; kt += 64) {
#pragma unroll
    for (int i = 0; i < 4; ++i) {
      const int idx = i * 256 + tid;
      const int r = idx >> 3;
      const int kq = (idx & 7) * 8;
      *reinterpret_cast<int4*>(&As[r][kq]) =
          *reinterpret_cast<const int4*>(&A[(size_t)(rowBase + r) * K + kt + kq]);
    }
#pragma unroll
    for (int i = 0; i < 2; ++i) {
      const int idx = i * 256 + tid;
      const int n = idx >> 3;
      const int kq = (idx & 7) * 8;
      *reinterpret_cast<int4*>(&Bs[n][kq]) =
          *reinterpret_cast<const int4*>(&Bt[(size_t)(colBase + n) * K + kt + kq]);
    }
    __syncthreads();
#pragma unroll
    for (int q = 0; q < 2; ++q) {
      const int ko = q * 32 + khi * 8;
      const bf16x8 a0 = *reinterpret_cast<const bf16x8*>(&As[w * 32 + r16][ko]);
      const bf16x8 a1 = *reinterpret_cast<const bf16x8*>(&As[w * 32 + 16 + r16][ko]);
      const bf16x8 b0 = *reinterpret_cast<const bf16x8*>(&Bs[r16][ko]);
      const bf16x8 b1 = *reinterpret_cast<const bf16x8*>(&Bs[16 + r16][ko]);
      const bf16x8 b2 = *reinterpret_cast<const bf16x8*>(&Bs[32 + r16][ko]);
      const bf16x8 b3 = *reinterpret_cast<const bf16x8*>(&Bs[48 + r16][ko]);
      acc[0][0] = __builtin_amdgcn_mfma_f32_16x16x32_bf16(a0, b0, acc[0][0], 0, 0, 0);
      acc[0][1] = __builtin_amdgcn_mfma_f32_16x16x32_bf16(a0, b1, acc[0][1], 0, 0, 0);
      acc[0][2] = __builtin_amdgcn_mfma_f32_16x16x32_bf16(a0, b2, acc[0][2], 0, 0, 0);
      acc[0][3] = __builtin_amdgcn_mfma_f32_16x16x32_bf16(a0, b3, acc[0][3], 0, 0, 0);
      acc[1][0] = __builtin_amdgcn_mfma_f32_16x16x32_bf16(a1, b0, acc[1][0], 0, 0, 0);
      acc[1][1] = __builtin_amdgcn_mfma_f32_16x16x32_bf16(a1, b1, acc[1][1], 0, 0, 0);
      acc[1][2] = __builtin_amdgcn_mfma_f32_16x16x32_bf16(a1, b2, acc[1][2], 0, 0, 0);
      acc[1][3] = __builtin_amdgcn_mfma_f32_16x16x32_bf16(a1, b3, acc[1][3], 0, 0, 0);
    }
    __syncthreads();
  }

#pragma unroll
  for (int n = 0; n < 4; ++n) {
    const float bv = bias[colBase + n * 16 + r16];
#pragma unroll
    for (int m = 0; m < 2; ++m) {
#pragma unroll
      for (int e = 0; e < 4; ++e) {
        const int rr = rowBase + w * 32 + m * 16 + khi * 4 + e;
        float v = acc[m][n][e] + bv;
        if (RELU) v = fmaxf(v, 0.f);
        C[(size_t)rr * N + colBase + n * 16 + r16] = f2b(v);
      }
    }
  }
}

// ---------------------------------------------------------------------------
// Kernel 3: final layer (K=64, N=3) + softmax. bf16 input, fp32 out.
// ---------------------------------------------------------------------------
__global__ __launch_bounds__(256) void final_softmax(const ushort* __restrict__ X,
                                                     const float* __restrict__ W,    // [64][3]
                                                     const float* __restrict__ bias, // [3]
                                                     float* __restrict__ Out) {      // [B][3]
  __shared__ float sw[64 * 3];
  __shared__ float sb[3];
  const int tid = threadIdx.x;
  if (tid < 64 * 3) sw[tid] = W[tid];
  if (tid < 3) sb[tid] = bias[tid];
  __syncthreads();

  const int row = blockIdx.x * 256 + tid;
  float d0 = sb[0], d1 = sb[1], d2 = sb[2];
#pragma unroll
  for (int k = 0; k < 64; k += 8) {
    const int4 xr = *reinterpret_cast<const int4*>(&X[(size_t)row * 64 + k]);
    const ushort* xp = reinterpret_cast<const ushort*>(&xr);
#pragma unroll
    for (int u = 0; u < 8; ++u) {
      const float x = b2f(xp[u]);
      d0 = fmaf(x, sw[(k + u) * 3 + 0], d0);
      d1 = fmaf(x, sw[(k + u) * 3 + 1], d1);
      d2 = fmaf(x, sw[(k + u) * 3 + 2], d2);
    }
  }
  const float m = fmaxf(d0, fmaxf(d1, d2));
  const float e0 = expf(d0 - m);
  const float e1 = expf(d1 - m);
  const float e2 = expf(d2 - m);
  const float inv = 1.0f / (e0 + e1 + e2);
  Out[(size_t)row * 3 + 0] = e0 * inv;
  Out[(size_t)row * 3 + 1] = e1 * inv;
  Out[(size_t)row * 3 + 2] = e2 * inv;
}

// ---------------------------------------------------------------------------
extern "C" void kernel_launch(void* const* d_in, const int* in_sizes, int n_in,
                              void* d_out, int out_size, void* d_ws, size_t ws_size,
                              hipStream_t stream) {
  const int* ids = (const int*)d_in[0];
  const float* E = (const float*)d_in[1];
  const float* W0 = (const float*)d_in[2];
  const float* b0 = (const float*)d_in[3];
  const float* W1 = (const float*)d_in[4];
  const float* b1 = (const float*)d_in[5];
  const float* W2 = (const float*)d_in[6];
  const float* b2 = (const float*)d_in[7];
  const float* W3 = (const float*)d_in[8];
  const float* b3 = (const float*)d_in[9];
  const float* W4 = (const float*)d_in[10];
  const float* b4 = (const float*)d_in[11];
  float* out = (float*)d_out;

  // Workspace: [Wt0..Wt3 | pad->1MB | xA 8MB | xB 8MB | Ebf 102.4MB]
  ushort* wt0 = (ushort*)d_ws;
  ushort* wt1 = wt0 + 512 * 512;
  ushort* wt2 = wt1 + 512 * 256;
  ushort* wt3 = wt2 + 256 * 128;
  ushort* xA = (ushort*)((char*)d_ws + (1u << 20));
  ushort* xB = xA + (size_t)BATCH * EMB;
  ushort* Ebf = (ushort*)((char*)d_ws + 17u * (1u << 20));
  const size_t need = 17u * (1u << 20) + (size_t)VOCAB * EMB * 2;
  const bool big = ws_size >= need;

  convert_weights<<<dim3(1024, 4), 256, 0, stream>>>(W0, W1, W2, W3, wt0, wt1, wt2, wt3);
  if (big) {
    convert_table<<<8192, 256, 0, stream>>>(E, Ebf);
    embed_bag_bf16<<<BATCH / 4, 256, 0, stream>>>(ids, Ebf, xA);                     // xA [8192,512]
  } else {
    embed_bag_f32<<<BATCH, 256, 0, stream>>>(ids, E, xA);
  }
  gemm_mfma<512, 512, true><<<dim3(8, 64), 256, 0, stream>>>(xA, wt0, b0, xB);       // xB [8192,512]
  gemm_mfma<512, 256, true><<<dim3(4, 64), 256, 0, stream>>>(xB, wt1, b1, xA);       // xA [8192,256]
  gemm_mfma<256, 128, true><<<dim3(2, 64), 256, 0, stream>>>(xA, wt2, b2, xB);       // xB [8192,128]
  gemm_mfma<128, 64, true><<<dim3(1, 64), 256, 0, stream>>>(xB, wt3, b3, xA);        // xA [8192,64]
  final_softmax<<<BATCH / 256, 256, 0, stream>>>(xA, W4, b4, out);                   // out [8192,3]
}